// Round 10
// baseline (106.108 us; speedup 1.0000x reference)
//
#include <hip/hip_runtime.h>
#include <math.h>
#include <stdint.h>

// ============================ R10 = DIAGNOSTIC ==============================
// R8 kernel with the convert+MFMA phase repeated REPS=8 times (loads issued
// once; asm register barriers force re-materialization each rep). The x8 on
// all three accumulated quantities cancels exactly in the cosine epilogue
// (8d / (sqrt(8a)*sqrt(8b)) = d/sqrt(ab)), so output matches R8 bit-for-~bit.
// Purpose: Delta(total) = 7 x pure-issue compute phase — finally separates
// memory-side time from compute-side time, since rocprof top-5 hides the
// kernel behind the harness's 42us poison fills.
// ===========================================================================

static constexpr int D_DIM   = 768;
static constexpr int NP      = 20;
static constexpr int NROWS   = 8192;
static constexpr int ROWS_PB = 16;                 // M-tile per block
static constexpr int BLOCKS  = NROWS / ROWS_PB;    // 512
static constexpr int WAVES   = 8;                  // 512 threads
static constexpr int KW      = D_DIM / WAVES;      // 96 k per wave
static constexpr int NSLICES = KW / 32;            // 3 MFMA k-steps
static constexpr int REPS    = 8;                  // diagnostic multiplier

typedef short  short8  __attribute__((ext_vector_type(8)));   // 8 bf16 (4 VGPRs)
typedef float  float4v __attribute__((ext_vector_type(4)));   // MFMA C/D + loads

__device__ __forceinline__ unsigned short bf16_rne(float x) {
  unsigned u = __float_as_uint(x);
  u += 0x7FFFu + ((u >> 16) & 1u);
  return (unsigned short)(u >> 16);
}
__device__ __forceinline__ float bf16f(unsigned short h) {
  return __uint_as_float(((unsigned)h) << 16);
}

__global__ __launch_bounds__(512, 4) void atte_cos_mfma(
    const float* __restrict__ repres,
    const float* __restrict__ max_att,
    const float* __restrict__ weight,
    float* __restrict__ out)
{
  const int tid  = threadIdx.x;
  const int wave = tid >> 6;           // 0..7 -> K range [wave*96, +96)
  const int lane = tid & 63;
  const int row0 = blockIdx.x * ROWS_PB;
  const int part = lane >> 4;          // 0..3 -> k-offset part*8 in MFMA frags
  const int mrow = lane & 15;          // A row within tile / B col index

  // Cross-wave reduce scratch only: 6 x 8 x 64 x 16 B = 48 KB.
  __shared__ __align__(16) float4v scratch[6][WAVES][64];

  const int kbase = wave * KW + part * 8;
  const float* ra = repres  + (size_t)(row0 + mrow) * D_DIM + kbase;
  const float* ma = max_att + (size_t)(row0 + mrow) * D_DIM + kbase;
  const int col0 = mrow;                                   // B cols 0..15
  const int col1 = (16 + mrow < NP) ? 16 + mrow : NP - 1;  // 16..19 (clamp junk)
  const float* wb0 = weight + (size_t)col0 * D_DIM + kbase;
  const float* wb1 = weight + (size_t)col1 * D_DIM + kbase;

  // ---- Issue all loads up front (24 dwordx4/wave). B first; plain cached
  //      loads (R9: nt regressed — half the input is L3-warm). ----
  float4 wf0[NSLICES][2], wf1[NSLICES][2];
#pragma unroll
  for (int s = 0; s < NSLICES; ++s) {
    wf0[s][0] = *(const float4*)(wb0 + s * 32);
    wf0[s][1] = *(const float4*)(wb0 + s * 32 + 4);
    wf1[s][0] = *(const float4*)(wb1 + s * 32);
    wf1[s][1] = *(const float4*)(wb1 + s * 32 + 4);
  }
  float4v ar[NSLICES][2], am[NSLICES][2];
#pragma unroll
  for (int s = 0; s < NSLICES; ++s) {
    ar[s][0] = *(const float4v*)(ra + s * 32);
    ar[s][1] = *(const float4v*)(ra + s * 32 + 4);
    am[s][0] = *(const float4v*)(ma + s * 32);
    am[s][1] = *(const float4v*)(ma + s * 32 + 4);
  }

  // ---- B -> w^2 bf16 fragments (once; small). ----
  short8 b0r[NSLICES], b1r[NSLICES];
#pragma unroll
  for (int s = 0; s < NSLICES; ++s) {
    const float* f0 = (const float*)&wf0[s][0];
    const float* f1 = (const float*)&wf1[s][0];
#pragma unroll
    for (int j = 0; j < 8; ++j) {
      b0r[s][j] = (short)bf16_rne(f0[j] * f0[j]);
      b1r[s][j] = (short)bf16_rne(f1[j] * f1[j]);
    }
  }

  // ---- Convert+MFMA phase, repeated REPS times (diagnostic). ----
  float4v acc[6] = {};  // [q*2 + ct]; q: 0=dot 1=||rw||^2 2=||mw||^2

  for (int rep = 0; rep < REPS; ++rep) {
    // Opaque barrier: compiler must treat A registers as freshly written each
    // rep -> the product/convert chain cannot be hoisted out of the loop.
#pragma unroll
    for (int s = 0; s < NSLICES; ++s) {
      asm volatile("" : "+v"(ar[s][0]), "+v"(ar[s][1]),
                        "+v"(am[s][0]), "+v"(am[s][1]));
    }

#pragma unroll
    for (int s = 0; s < NSLICES; ++s) {
      const float* rv = (const float*)&ar[s][0];
      const float* mv = (const float*)&am[s][0];

      short8 a0h, a0l, a1h, a2h;
#pragma unroll
      for (int j = 0; j < 8; ++j) {
        const float pm = rv[j] * mv[j];
        const float pr = rv[j] * rv[j];
        const float pq = mv[j] * mv[j];
        const unsigned short h = bf16_rne(pm);
        a0h[j] = (short)h;
        a0l[j] = (short)bf16_rne(pm - bf16f(h));
        a1h[j] = (short)bf16_rne(pr);
        a2h[j] = (short)bf16_rne(pq);
      }

      acc[0] = __builtin_amdgcn_mfma_f32_16x16x32_bf16(a0h, b0r[s], acc[0], 0, 0, 0);
      acc[0] = __builtin_amdgcn_mfma_f32_16x16x32_bf16(a0l, b0r[s], acc[0], 0, 0, 0);
      acc[1] = __builtin_amdgcn_mfma_f32_16x16x32_bf16(a0h, b1r[s], acc[1], 0, 0, 0);
      acc[1] = __builtin_amdgcn_mfma_f32_16x16x32_bf16(a0l, b1r[s], acc[1], 0, 0, 0);
      acc[2] = __builtin_amdgcn_mfma_f32_16x16x32_bf16(a1h, b0r[s], acc[2], 0, 0, 0);
      acc[3] = __builtin_amdgcn_mfma_f32_16x16x32_bf16(a1h, b1r[s], acc[3], 0, 0, 0);
      acc[4] = __builtin_amdgcn_mfma_f32_16x16x32_bf16(a2h, b0r[s], acc[4], 0, 0, 0);
      acc[5] = __builtin_amdgcn_mfma_f32_16x16x32_bf16(a2h, b1r[s], acc[5], 0, 0, 0);
    }
  }

  // ---- Cross-wave K reduction (8 partials per output). The x REPS factor
  //      cancels in the cosine: (R*d)/(sqrt(R*a)*sqrt(R*b)) = d/sqrt(ab). ----
#pragma unroll
  for (int qc = 0; qc < 6; ++qc)
    scratch[qc][wave][lane] = acc[qc];
  __syncthreads();

  if (wave < 2) {                // wave = column-tile; same (row,col)->lane map
    const int ct = wave;
    float4v c0 = {}, c1 = {}, c2 = {};
#pragma unroll
    for (int wv = 0; wv < WAVES; ++wv) {
      c0 += scratch[0 * 2 + ct][wv][lane];
      c1 += scratch[1 * 2 + ct][wv][lane];
      c2 += scratch[2 * 2 + ct][wv][lane];
    }
    const int col = ct * 16 + (lane & 15);
    if (col < NP) {
      const int rbase = row0 + (lane >> 4) * 4;  // C row = (lane>>4)*4 + reg
#pragma unroll
      for (int r = 0; r < 4; ++r) {
        const float n1 = fmaxf(sqrtf(c1[r]), 1e-8f);
        const float n2 = fmaxf(sqrtf(c2[r]), 1e-8f);
        out[(size_t)(rbase + r) * NP + col] = c0[r] / (n1 * n2);
      }
    }
  }
}

extern "C" void kernel_launch(void* const* d_in, const int* in_sizes, int n_in,
                              void* d_out, int out_size, void* d_ws, size_t ws_size,
                              hipStream_t stream) {
  const float* repres  = (const float*)d_in[0];
  const float* max_att = (const float*)d_in[1];
  const float* weight  = (const float*)d_in[2];
  float* out = (float*)d_out;

  atte_cos_mfma<<<BLOCKS, 512, 0, stream>>>(repres, max_att, weight, out);
}

// Round 11
// 96.473 us; speedup vs baseline: 1.0999x; 1.0999x over previous
//
#include <hip/hip_runtime.h>
#include <math.h>
#include <stdint.h>

// R10 diagnostic result: compute phase = 2.0us (matches model); kernel ~23us
// => ~21us is memory-side for 25MB HBM-miss + ~70MB cache traffic (model: 4-6us).
// R6 (contiguous DMA) == R8 (scattered reg loads) => not request-rate.
// R11 experiment: split latency from bandwidth. Pass 1 = pure streaming
// prefetch (latency-insensitive, full-BW) warming L2/L3; pass 2 = unchanged
// R8 compute, now hitting warm caches. If memory-side was latency exposure,
// total drops ~10us; if it's an effective-BW floor, total is unchanged.

static constexpr int D_DIM   = 768;
static constexpr int NP      = 20;
static constexpr int NROWS   = 8192;
static constexpr int ROWS_PB = 16;                 // M-tile per block
static constexpr int BLOCKS  = NROWS / ROWS_PB;    // 512
static constexpr int WAVES   = 8;                  // 512 threads
static constexpr int KW      = D_DIM / WAVES;      // 96 k per wave
static constexpr int NSLICES = KW / 32;            // 3 MFMA k-steps

typedef short  short8  __attribute__((ext_vector_type(8)));   // 8 bf16 (4 VGPRs)
typedef float  float4v __attribute__((ext_vector_type(4)));   // MFMA C/D + loads

__device__ __forceinline__ unsigned short bf16_rne(float x) {
  unsigned u = __float_as_uint(x);
  u += 0x7FFFu + ((u >> 16) & 1u);
  return (unsigned short)(u >> 16);
}
__device__ __forceinline__ float bf16f(unsigned short h) {
  return __uint_as_float(((unsigned)h) << 16);
}

// ---- Pass 1: streaming prefetch of repres+max_att into L2/L3. ----
// 1536 blocks x 256 threads x 8 float4 = 3,145,728 float4 = 48 MB... (2 inputs
// x 1,572,864 float4 each). 8 independent loads/thread -> no latency on the
// critical path; per-block max stored to d_ws (prevents DCE; ws is scratch).
static constexpr size_t NF4 = (size_t)NROWS * D_DIM / 4;   // float4 per input
__global__ __launch_bounds__(256) void warm_kernel(
    const float4v* __restrict__ a, const float4v* __restrict__ b,
    float* __restrict__ ws)
{
  const size_t base = (size_t)blockIdx.x * 2048 + threadIdx.x;
  float4v v[8];
#pragma unroll
  for (int j = 0; j < 8; ++j) {
    const size_t f = base + (size_t)j * 256;
    v[j] = (f < NF4) ? a[f] : b[f - NF4];
  }
  float mx = v[0][0];
#pragma unroll
  for (int j = 0; j < 8; ++j)
#pragma unroll
    for (int c = 0; c < 4; ++c) mx = fmaxf(mx, v[j][c]);
  // per-wave fold via DPP-free shuffle is overkill; one store per thread is
  // tiny (393 KB total) and keeps the loads alive.
  ws[(size_t)blockIdx.x * 256 + threadIdx.x] = mx;
}

// ---- Pass 2: unchanged R8 MFMA kernel. ----
__global__ __launch_bounds__(512, 4) void atte_cos_mfma(
    const float* __restrict__ repres,
    const float* __restrict__ max_att,
    const float* __restrict__ weight,
    float* __restrict__ out)
{
  const int tid  = threadIdx.x;
  const int wave = tid >> 6;           // 0..7 -> K range [wave*96, +96)
  const int lane = tid & 63;
  const int row0 = blockIdx.x * ROWS_PB;
  const int part = lane >> 4;          // 0..3 -> k-offset part*8 in MFMA frags
  const int mrow = lane & 15;          // A row within tile / B col index

  __shared__ __align__(16) float4v scratch[6][WAVES][64];

  const int kbase = wave * KW + part * 8;
  const float* ra = repres  + (size_t)(row0 + mrow) * D_DIM + kbase;
  const float* ma = max_att + (size_t)(row0 + mrow) * D_DIM + kbase;
  const int col0 = mrow;
  const int col1 = (16 + mrow < NP) ? 16 + mrow : NP - 1;
  const float* wb0 = weight + (size_t)col0 * D_DIM + kbase;
  const float* wb1 = weight + (size_t)col1 * D_DIM + kbase;

  float4 wf0[NSLICES][2], wf1[NSLICES][2];
#pragma unroll
  for (int s = 0; s < NSLICES; ++s) {
    wf0[s][0] = *(const float4*)(wb0 + s * 32);
    wf0[s][1] = *(const float4*)(wb0 + s * 32 + 4);
    wf1[s][0] = *(const float4*)(wb1 + s * 32);
    wf1[s][1] = *(const float4*)(wb1 + s * 32 + 4);
  }
  float4v ar[NSLICES][2], am[NSLICES][2];
#pragma unroll
  for (int s = 0; s < NSLICES; ++s) {
    ar[s][0] = *(const float4v*)(ra + s * 32);
    ar[s][1] = *(const float4v*)(ra + s * 32 + 4);
    am[s][0] = *(const float4v*)(ma + s * 32);
    am[s][1] = *(const float4v*)(ma + s * 32 + 4);
  }

  short8 b0r[NSLICES], b1r[NSLICES];
#pragma unroll
  for (int s = 0; s < NSLICES; ++s) {
    const float* f0 = (const float*)&wf0[s][0];
    const float* f1 = (const float*)&wf1[s][0];
#pragma unroll
    for (int j = 0; j < 8; ++j) {
      b0r[s][j] = (short)bf16_rne(f0[j] * f0[j]);
      b1r[s][j] = (short)bf16_rne(f1[j] * f1[j]);
    }
  }

  float4v acc[6] = {};  // [q*2 + ct]; q: 0=dot 1=||rw||^2 2=||mw||^2

#pragma unroll
  for (int s = 0; s < NSLICES; ++s) {
    const float* rv = (const float*)&ar[s][0];
    const float* mv = (const float*)&am[s][0];

    short8 a0h, a0l, a1h, a2h;
#pragma unroll
    for (int j = 0; j < 8; ++j) {
      const float pm = rv[j] * mv[j];
      const float pr = rv[j] * rv[j];
      const float pq = mv[j] * mv[j];
      const unsigned short h = bf16_rne(pm);
      a0h[j] = (short)h;
      a0l[j] = (short)bf16_rne(pm - bf16f(h));
      a1h[j] = (short)bf16_rne(pr);
      a2h[j] = (short)bf16_rne(pq);
    }

    acc[0] = __builtin_amdgcn_mfma_f32_16x16x32_bf16(a0h, b0r[s], acc[0], 0, 0, 0);
    acc[0] = __builtin_amdgcn_mfma_f32_16x16x32_bf16(a0l, b0r[s], acc[0], 0, 0, 0);
    acc[1] = __builtin_amdgcn_mfma_f32_16x16x32_bf16(a0h, b1r[s], acc[1], 0, 0, 0);
    acc[1] = __builtin_amdgcn_mfma_f32_16x16x32_bf16(a0l, b1r[s], acc[1], 0, 0, 0);
    acc[2] = __builtin_amdgcn_mfma_f32_16x16x32_bf16(a1h, b0r[s], acc[2], 0, 0, 0);
    acc[3] = __builtin_amdgcn_mfma_f32_16x16x32_bf16(a1h, b1r[s], acc[3], 0, 0, 0);
    acc[4] = __builtin_amdgcn_mfma_f32_16x16x32_bf16(a2h, b0r[s], acc[4], 0, 0, 0);
    acc[5] = __builtin_amdgcn_mfma_f32_16x16x32_bf16(a2h, b1r[s], acc[5], 0, 0, 0);
  }

#pragma unroll
  for (int qc = 0; qc < 6; ++qc)
    scratch[qc][wave][lane] = acc[qc];
  __syncthreads();

  if (wave < 2) {
    const int ct = wave;
    float4v c0 = {}, c1 = {}, c2 = {};
#pragma unroll
    for (int wv = 0; wv < WAVES; ++wv) {
      c0 += scratch[0 * 2 + ct][wv][lane];
      c1 += scratch[1 * 2 + ct][wv][lane];
      c2 += scratch[2 * 2 + ct][wv][lane];
    }
    const int col = ct * 16 + (lane & 15);
    if (col < NP) {
      const int rbase = row0 + (lane >> 4) * 4;  // C row = (lane>>4)*4 + reg
#pragma unroll
      for (int r = 0; r < 4; ++r) {
        const float n1 = fmaxf(sqrtf(c1[r]), 1e-8f);
        const float n2 = fmaxf(sqrtf(c2[r]), 1e-8f);
        out[(size_t)(rbase + r) * NP + col] = c0[r] / (n1 * n2);
      }
    }
  }
}

extern "C" void kernel_launch(void* const* d_in, const int* in_sizes, int n_in,
                              void* d_out, int out_size, void* d_ws, size_t ws_size,
                              hipStream_t stream) {
  const float* repres  = (const float*)d_in[0];
  const float* max_att = (const float*)d_in[1];
  const float* weight  = (const float*)d_in[2];
  float* out = (float*)d_out;

  // Pass 1: warm L2/L3 with both streaming inputs (latency-insensitive).
  warm_kernel<<<1536, 256, 0, stream>>>(
      (const float4v*)repres, (const float4v*)max_att, (float*)d_ws);
  // Pass 2: compute (unchanged R8).
  atte_cos_mfma<<<BLOCKS, 512, 0, stream>>>(repres, max_att, weight, out);
}